// Round 1
// baseline (1233.578 us; speedup 1.0000x reference)
//
#include <hip/hip_runtime.h>
#include <hip/hip_bf16.h>
#include <math.h>

#define NTOK 8192     // B*T
#define DD   1024
#define HH   4096
#define NE   8
#define SLOT_CAP 17408  // 16384 + 8*128 padding worst case
#define BM 128
#define BN 128
#define BK 64
#define KPAD 8

typedef __bf16 bf16;
typedef __bf16 bf16x8 __attribute__((ext_vector_type(8)));
typedef __bf16 bf16x4 __attribute__((ext_vector_type(4)));
typedef float  f32x4  __attribute__((ext_vector_type(4)));

__device__ __forceinline__ float softplus_f(float v) {
  return fmaxf(v, 0.f) + log1pf(expf(-fabsf(v)));
}

// ---------------- K1: gating (1 wave per token) ----------------
__global__ __launch_bounds__(64) void moe_gate_kernel(
    const float* __restrict__ x, const float* __restrict__ noise,
    const float* __restrict__ gate_w, const float* __restrict__ gate_b,
    const float* __restrict__ var_w,  const float* __restrict__ var_b,
    float* __restrict__ coef2, int* __restrict__ t2e, int* __restrict__ counts)
{
  const int t = blockIdx.x;
  const int lane = threadIdx.x;
  const float* xt = x + (size_t)t * DD;
  float pg[NE], pv[NE];
  #pragma unroll
  for (int e = 0; e < NE; ++e) { pg[e] = 0.f; pv[e] = 0.f; }
  #pragma unroll 4
  for (int i = 0; i < DD / 64; ++i) {
    const int d = lane + i * 64;
    const float xv = xt[d];
    #pragma unroll
    for (int e = 0; e < NE; ++e) {
      pg[e] = fmaf(xv, gate_w[e * DD + d], pg[e]);
      pv[e] = fmaf(xv, var_w[e * DD + d], pv[e]);
    }
  }
  #pragma unroll
  for (int e = 0; e < NE; ++e) {
    #pragma unroll
    for (int off = 32; off; off >>= 1) {
      pg[e] += __shfl_xor(pg[e], off);
      pv[e] += __shfl_xor(pv[e], off);
    }
  }
  if (lane == 0) {
    float noisy[NE];
    #pragma unroll
    for (int e = 0; e < NE; ++e) {
      const float lg = pg[e] + gate_b[e];
      const float sd = softplus_f(pv[e] + var_b[e]);
      noisy[e] = lg + noise[t * NE + e] * sd;
    }
    int i1 = 0; float n1 = noisy[0];
    #pragma unroll
    for (int e = 1; e < NE; ++e) if (noisy[e] > n1) { n1 = noisy[e]; i1 = e; }
    int i2 = -1; float n2 = -3.0e38f;
    #pragma unroll
    for (int e = 0; e < NE; ++e) if (e != i1 && noisy[e] > n2) { n2 = noisy[e]; i2 = e; }
    const float e2 = expf(n2 - n1);
    const float den = 1.f + e2;
    coef2[t * 2 + 0] = 1.f / den;
    coef2[t * 2 + 1] = e2 / den;
    t2e[t * 2 + 0] = i1;
    t2e[t * 2 + 1] = i2;
    atomicAdd(&counts[i1], 1);
    atomicAdd(&counts[i2], 1);
  }
}

// ---------------- K2: padded segment offsets ----------------
__global__ void moe_offsets_kernel(const int* __restrict__ counts, int* __restrict__ po) {
  if (threadIdx.x == 0) {
    int acc = 0;
    po[0] = 0;
    for (int e = 0; e < NE; ++e) {
      acc += ((counts[e] + BM - 1) / BM) * BM;
      po[e + 1] = acc;
    }
  }
}

// ---------------- K3: scatter tokens into padded slots ----------------
__global__ __launch_bounds__(256) void moe_scatter_kernel(
    const int* __restrict__ t2e, const int* __restrict__ po, int* __restrict__ cnt2,
    int* __restrict__ assign_tok, int* __restrict__ slot_of)
{
  const int t = blockIdx.x * 256 + threadIdx.x;
  if (t >= NTOK) return;
  #pragma unroll
  for (int k = 0; k < 2; ++k) {
    const int e = t2e[t * 2 + k];
    const int pos = atomicAdd(&cnt2[e], 1);
    const int slot = po[e] + pos;
    assign_tok[slot] = t;
    slot_of[t * 2 + k] = slot;
  }
}

// ---------------- K4: x -> bf16 ----------------
__global__ __launch_bounds__(256) void moe_cvtx_kernel(const float* __restrict__ x,
                                                       bf16* __restrict__ xb) {
  const int i = blockIdx.x * 256 + threadIdx.x;  // quads, grid sized exactly
  const float4 f = ((const float4*)x)[i];
  bf16x4 v;
  v[0] = (bf16)f.x; v[1] = (bf16)f.y; v[2] = (bf16)f.z; v[3] = (bf16)f.w;
  ((bf16x4*)xb)[i] = v;
}

// ---------------- K5: grouped GEMM layer 1: h = relu(x @ w1e^T + b1e) ----------------
__global__ __launch_bounds__(256) void moe_ffn1_kernel(
    const bf16* __restrict__ xb, const float* __restrict__ w1, const float* __restrict__ b1,
    const int* __restrict__ assign_tok, const int* __restrict__ po,
    bf16* __restrict__ h, int chunk_base)
{
  __shared__ bf16 As[BM][BK + KPAD];
  __shared__ bf16 Bs[BN][BK + KPAD];
  __shared__ int toks[BM];
  const int po8 = po[NE];
  const int row0 = chunk_base + blockIdx.x * BM;
  if (row0 >= po8) return;
  int e = 0;
  while (row0 >= po[e + 1]) ++e;
  const int bn0 = blockIdx.y * BN;
  const float* w1e = w1 + (size_t)e * HH * DD;
  const int tid = threadIdx.x;
  if (tid < BM) {
    const int s = assign_tok[row0 + tid];
    toks[tid] = s < 0 ? 0 : s;
  }
  __syncthreads();
  const int lane = tid & 63;
  const int wave = tid >> 6;
  const int wm = (wave >> 1) * 64, wn = (wave & 1) * 64;
  const int la = lane & 15, lb = (lane >> 4) * 8;
  f32x4 acc[4][4];
  #pragma unroll
  for (int m = 0; m < 4; ++m)
    #pragma unroll
    for (int n = 0; n < 4; ++n) acc[m][n] = {0.f, 0.f, 0.f, 0.f};

  for (int k0 = 0; k0 < DD; k0 += BK) {
    #pragma unroll
    for (int i = 0; i < 4; ++i) {        // A: 128x64 bf16, 16B per thread-chunk
      const int c = tid + i * 256;
      const int r = c >> 3, kk = (c & 7) * 8;
      const int4 v = *(const int4*)(xb + (size_t)toks[r] * DD + k0 + kk);
      *(int4*)(&As[r][kk]) = v;
    }
    #pragma unroll
    for (int i = 0; i < 4; ++i) {        // B: 128x64 f32 -> bf16
      const int c = tid + i * 256;
      const int r = c >> 3, kk = (c & 7) * 8;
      const float4 f0 = *(const float4*)(w1e + (size_t)(bn0 + r) * DD + k0 + kk);
      const float4 f1 = *(const float4*)(w1e + (size_t)(bn0 + r) * DD + k0 + kk + 4);
      bf16x8 v;
      v[0] = (bf16)f0.x; v[1] = (bf16)f0.y; v[2] = (bf16)f0.z; v[3] = (bf16)f0.w;
      v[4] = (bf16)f1.x; v[5] = (bf16)f1.y; v[6] = (bf16)f1.z; v[7] = (bf16)f1.w;
      *(bf16x8*)(&Bs[r][kk]) = v;
    }
    __syncthreads();
    #pragma unroll
    for (int ks = 0; ks < 2; ++ks) {
      bf16x8 af[4], bff[4];
      #pragma unroll
      for (int m = 0; m < 4; ++m) af[m] = *(const bf16x8*)(&As[wm + m * 16 + la][ks * 32 + lb]);
      #pragma unroll
      for (int n = 0; n < 4; ++n) bff[n] = *(const bf16x8*)(&Bs[wn + n * 16 + la][ks * 32 + lb]);
      #pragma unroll
      for (int m = 0; m < 4; ++m)
        #pragma unroll
        for (int n = 0; n < 4; ++n)
          acc[m][n] = __builtin_amdgcn_mfma_f32_16x16x32_bf16(af[m], bff[n], acc[m][n], 0, 0, 0);
    }
    __syncthreads();
  }

  const int hrow0 = row0 - chunk_base;
  #pragma unroll
  for (int n = 0; n < 4; ++n) {
    const int col = bn0 + wn + n * 16 + la;
    const float bb = b1[e * HH + col];
    #pragma unroll
    for (int m = 0; m < 4; ++m) {
      const int rbase = wm + m * 16 + ((lane >> 4) * 4);
      #pragma unroll
      for (int r = 0; r < 4; ++r) {
        float v = acc[m][n][r] + bb;
        v = v > 0.f ? v : 0.f;
        h[(size_t)(hrow0 + rbase + r) * HH + col] = (bf16)v;
      }
    }
  }
}

// ---------------- K6: grouped GEMM layer 2: y = h @ w2e^T + b2e ----------------
__global__ __launch_bounds__(256) void moe_ffn2_kernel(
    const bf16* __restrict__ h, const float* __restrict__ w2, const float* __restrict__ b2,
    const int* __restrict__ assign_tok, const int* __restrict__ po,
    bf16* __restrict__ y, int chunk_base)
{
  __shared__ bf16 As[BM][BK + KPAD];
  __shared__ bf16 Bs[BN][BK + KPAD];
  __shared__ int toks[BM];
  const int po8 = po[NE];
  const int row0 = chunk_base + blockIdx.x * BM;
  if (row0 >= po8) return;
  int e = 0;
  while (row0 >= po[e + 1]) ++e;
  const int bn0 = blockIdx.y * BN;
  const float* w2e = w2 + (size_t)e * DD * HH;
  const int tid = threadIdx.x;
  if (tid < BM) toks[tid] = assign_tok[row0 + tid];
  __syncthreads();
  const int lane = tid & 63;
  const int wave = tid >> 6;
  const int wm = (wave >> 1) * 64, wn = (wave & 1) * 64;
  const int la = lane & 15, lb = (lane >> 4) * 8;
  const int arow0 = row0 - chunk_base;
  f32x4 acc[4][4];
  #pragma unroll
  for (int m = 0; m < 4; ++m)
    #pragma unroll
    for (int n = 0; n < 4; ++n) acc[m][n] = {0.f, 0.f, 0.f, 0.f};

  for (int k0 = 0; k0 < HH; k0 += BK) {
    #pragma unroll
    for (int i = 0; i < 4; ++i) {        // A: h rows (contiguous slots)
      const int c = tid + i * 256;
      const int r = c >> 3, kk = (c & 7) * 8;
      const int4 v = *(const int4*)(h + (size_t)(arow0 + r) * HH + k0 + kk);
      *(int4*)(&As[r][kk]) = v;
    }
    #pragma unroll
    for (int i = 0; i < 4; ++i) {        // B: w2e rows f32 -> bf16
      const int c = tid + i * 256;
      const int r = c >> 3, kk = (c & 7) * 8;
      const float4 f0 = *(const float4*)(w2e + (size_t)(bn0 + r) * HH + k0 + kk);
      const float4 f1 = *(const float4*)(w2e + (size_t)(bn0 + r) * HH + k0 + kk + 4);
      bf16x8 v;
      v[0] = (bf16)f0.x; v[1] = (bf16)f0.y; v[2] = (bf16)f0.z; v[3] = (bf16)f0.w;
      v[4] = (bf16)f1.x; v[5] = (bf16)f1.y; v[6] = (bf16)f1.z; v[7] = (bf16)f1.w;
      *(bf16x8*)(&Bs[r][kk]) = v;
    }
    __syncthreads();
    #pragma unroll
    for (int ks = 0; ks < 2; ++ks) {
      bf16x8 af[4], bff[4];
      #pragma unroll
      for (int m = 0; m < 4; ++m) af[m] = *(const bf16x8*)(&As[wm + m * 16 + la][ks * 32 + lb]);
      #pragma unroll
      for (int n = 0; n < 4; ++n) bff[n] = *(const bf16x8*)(&Bs[wn + n * 16 + la][ks * 32 + lb]);
      #pragma unroll
      for (int m = 0; m < 4; ++m)
        #pragma unroll
        for (int n = 0; n < 4; ++n)
          acc[m][n] = __builtin_amdgcn_mfma_f32_16x16x32_bf16(af[m], bff[n], acc[m][n], 0, 0, 0);
    }
    __syncthreads();
  }

  #pragma unroll
  for (int n = 0; n < 4; ++n) {
    const int col = bn0 + wn + n * 16 + la;
    const float bb = b2[e * DD + col];
    #pragma unroll
    for (int m = 0; m < 4; ++m) {
      const int rbase = wm + m * 16 + ((lane >> 4) * 4);
      #pragma unroll
      for (int r = 0; r < 4; ++r) {
        const int trow = rbase + r;
        if (toks[trow] >= 0)
          y[(size_t)(row0 + trow) * DD + col] = (bf16)(acc[m][n][r] + bb);
      }
    }
  }
}

// ---------------- K7: combine out[t] = c0*y[s0] + c1*y[s1] ----------------
__global__ __launch_bounds__(256) void moe_combine_kernel(
    const bf16* __restrict__ y, const int* __restrict__ slot_of,
    const float* __restrict__ coef2, float* __restrict__ out)
{
  const int t = blockIdx.x;
  const int dq = threadIdx.x;  // 256 threads * 4 elems = 1024
  const int s0 = slot_of[t * 2 + 0], s1 = slot_of[t * 2 + 1];
  const float c0 = coef2[t * 2 + 0], c1 = coef2[t * 2 + 1];
  const bf16x4 y0 = ((const bf16x4*)(y + (size_t)s0 * DD))[dq];
  const bf16x4 y1 = ((const bf16x4*)(y + (size_t)s1 * DD))[dq];
  float4 o;
  o.x = c0 * (float)y0[0] + c1 * (float)y1[0];
  o.y = c0 * (float)y0[1] + c1 * (float)y1[1];
  o.z = c0 * (float)y0[2] + c1 * (float)y1[2];
  o.w = c0 * (float)y0[3] + c1 * (float)y1[3];
  ((float4*)(out + (size_t)t * DD))[dq] = o;
}

extern "C" void kernel_launch(void* const* d_in, const int* in_sizes, int n_in,
                              void* d_out, int out_size, void* d_ws, size_t ws_size,
                              hipStream_t stream) {
  const float* x      = (const float*)d_in[0];
  const float* noise  = (const float*)d_in[1];
  const float* gate_w = (const float*)d_in[2];
  const float* gate_b = (const float*)d_in[3];
  const float* var_w  = (const float*)d_in[4];
  const float* var_b  = (const float*)d_in[5];
  const float* w1     = (const float*)d_in[6];
  const float* b1     = (const float*)d_in[7];
  const float* w2     = (const float*)d_in[8];
  const float* b2     = (const float*)d_in[9];
  float* out = (float*)d_out;
  (void)in_sizes; (void)n_in; (void)out_size;

  char* ws = (char*)d_ws;
  size_t off = 0;
  auto alloc = [&](size_t bytes) {
    off = (off + 255) & ~(size_t)255;
    size_t o = off;
    off += bytes;
    return o;
  };
  bf16*  xb         = (bf16*)(ws + alloc((size_t)NTOK * DD * 2));
  float* coef2      = (float*)(ws + alloc((size_t)NTOK * 2 * 4));
  int*   t2e        = (int*)(ws + alloc((size_t)NTOK * 2 * 4));
  int*   slot_of    = (int*)(ws + alloc((size_t)NTOK * 2 * 4));
  int*   counts     = (int*)(ws + alloc(64));   // counts[8] + cnt2[8]
  int*   cnt2       = counts + 8;
  int*   po         = (int*)(ws + alloc(64));
  int*   assign_tok = (int*)(ws + alloc((size_t)SLOT_CAP * 4));
  bf16*  y          = (bf16*)(ws + alloc((size_t)SLOT_CAP * DD * 2));
  off = (off + 255) & ~(size_t)255;
  const size_t h_avail = ws_size > off ? ws_size - off : 0;
  int chunk_rows = (int)(h_avail / ((size_t)HH * 2));
  chunk_rows = (chunk_rows / BM) * BM;
  if (chunk_rows < BM) chunk_rows = BM;
  if (chunk_rows > SLOT_CAP) chunk_rows = SLOT_CAP;
  bf16* hbuf = (bf16*)(ws + off);

  hipMemsetAsync(counts, 0, 64, stream);                       // counts + cnt2
  hipMemsetAsync(assign_tok, 0xFF, (size_t)SLOT_CAP * 4, stream);  // -1

  moe_gate_kernel<<<NTOK, 64, 0, stream>>>(x, noise, gate_w, gate_b, var_w, var_b,
                                           coef2, t2e, counts);
  moe_offsets_kernel<<<1, 64, 0, stream>>>(counts, po);
  moe_scatter_kernel<<<NTOK / 256, 256, 0, stream>>>(t2e, po, cnt2, assign_tok, slot_of);
  moe_cvtx_kernel<<<(NTOK * DD / 4) / 256, 256, 0, stream>>>(x, xb);

  const int rounds = (SLOT_CAP + chunk_rows - 1) / chunk_rows;
  for (int r = 0; r < rounds; ++r) {
    const int cb = r * chunk_rows;
    dim3 g1(chunk_rows / BM, HH / BN);
    moe_ffn1_kernel<<<g1, 256, 0, stream>>>(xb, w1, b1, assign_tok, po, hbuf, cb);
    dim3 g2(chunk_rows / BM, DD / BN);
    moe_ffn2_kernel<<<g2, 256, 0, stream>>>(hbuf, w2, b2, assign_tok, po, y, cb);
  }
  moe_combine_kernel<<<NTOK, 256, 0, stream>>>(y, slot_of, coef2, out);
}

// Round 2
// 954.433 us; speedup vs baseline: 1.2925x; 1.2925x over previous
//
#include <hip/hip_runtime.h>
#include <hip/hip_bf16.h>
#include <math.h>

#define NTOK 8192     // B*T
#define DD   1024
#define HH   4096
#define NE   8
#define SLOT_CAP 17408  // 16384 + 8*128 padding worst case
#define BM 128
#define BN 128
#define BK 64

typedef __bf16 bf16;
typedef __bf16 bf16x8 __attribute__((ext_vector_type(8)));
typedef __bf16 bf16x4 __attribute__((ext_vector_type(4)));
typedef float  f32x4  __attribute__((ext_vector_type(4)));

typedef __attribute__((address_space(3))) unsigned char lds_u8;
typedef const __attribute__((address_space(1))) unsigned char g_u8;

__device__ __forceinline__ void gload16(const bf16* g, bf16* l) {
  __builtin_amdgcn_global_load_lds((g_u8*)g, (lds_u8*)l, 16, 0, 0);
}

__device__ __forceinline__ float softplus_f(float v) {
  return fmaxf(v, 0.f) + log1pf(expf(-fabsf(v)));
}

// ---------------- K1: gating (1 wave per token) ----------------
__global__ __launch_bounds__(64) void moe_gate_kernel(
    const float* __restrict__ x, const float* __restrict__ noise,
    const float* __restrict__ gate_w, const float* __restrict__ gate_b,
    const float* __restrict__ var_w,  const float* __restrict__ var_b,
    float* __restrict__ coef2, int* __restrict__ t2e, int* __restrict__ counts)
{
  const int t = blockIdx.x;
  const int lane = threadIdx.x;
  const float* xt = x + (size_t)t * DD;
  float pg[NE], pv[NE];
  #pragma unroll
  for (int e = 0; e < NE; ++e) { pg[e] = 0.f; pv[e] = 0.f; }
  #pragma unroll 4
  for (int i = 0; i < DD / 64; ++i) {
    const int d = lane + i * 64;
    const float xv = xt[d];
    #pragma unroll
    for (int e = 0; e < NE; ++e) {
      pg[e] = fmaf(xv, gate_w[e * DD + d], pg[e]);
      pv[e] = fmaf(xv, var_w[e * DD + d], pv[e]);
    }
  }
  #pragma unroll
  for (int e = 0; e < NE; ++e) {
    #pragma unroll
    for (int off = 32; off; off >>= 1) {
      pg[e] += __shfl_xor(pg[e], off);
      pv[e] += __shfl_xor(pv[e], off);
    }
  }
  if (lane == 0) {
    float noisy[NE];
    #pragma unroll
    for (int e = 0; e < NE; ++e) {
      const float lg = pg[e] + gate_b[e];
      const float sd = softplus_f(pv[e] + var_b[e]);
      noisy[e] = lg + noise[t * NE + e] * sd;
    }
    int i1 = 0; float n1 = noisy[0];
    #pragma unroll
    for (int e = 1; e < NE; ++e) if (noisy[e] > n1) { n1 = noisy[e]; i1 = e; }
    int i2 = -1; float n2 = -3.0e38f;
    #pragma unroll
    for (int e = 0; e < NE; ++e) if (e != i1 && noisy[e] > n2) { n2 = noisy[e]; i2 = e; }
    const float e2 = expf(n2 - n1);
    const float den = 1.f + e2;
    coef2[t * 2 + 0] = 1.f / den;
    coef2[t * 2 + 1] = e2 / den;
    t2e[t * 2 + 0] = i1;
    t2e[t * 2 + 1] = i2;
    atomicAdd(&counts[i1], 1);
    atomicAdd(&counts[i2], 1);
  }
}

// ---------------- K2: padded segment offsets ----------------
__global__ void moe_offsets_kernel(const int* __restrict__ counts, int* __restrict__ po) {
  if (threadIdx.x == 0) {
    int acc = 0;
    po[0] = 0;
    for (int e = 0; e < NE; ++e) {
      acc += ((counts[e] + BM - 1) / BM) * BM;
      po[e + 1] = acc;
    }
  }
}

// ---------------- K3: scatter tokens into padded slots ----------------
__global__ __launch_bounds__(256) void moe_scatter_kernel(
    const int* __restrict__ t2e, const float* __restrict__ coef2,
    const int* __restrict__ po, int* __restrict__ cnt2,
    int* __restrict__ assign_tok, float* __restrict__ slot_coef)
{
  const int t = blockIdx.x * 256 + threadIdx.x;
  if (t >= NTOK) return;
  #pragma unroll
  for (int k = 0; k < 2; ++k) {
    const int e = t2e[t * 2 + k];
    const int pos = atomicAdd(&cnt2[e], 1);
    const int slot = po[e] + pos;
    assign_tok[slot] = t;
    slot_coef[slot] = coef2[t * 2 + k];
  }
}

// ---------------- K4: f32 -> bf16 converter (grid-stride over float4) ----------------
__global__ __launch_bounds__(256) void cvt_bf16_kernel(const float* __restrict__ src,
                                                       bf16* __restrict__ dst, int n4) {
  for (int i = blockIdx.x * 256 + threadIdx.x; i < n4; i += gridDim.x * 256) {
    const float4 f = ((const float4*)src)[i];
    bf16x4 v;
    v[0] = (bf16)f.x; v[1] = (bf16)f.y; v[2] = (bf16)f.z; v[3] = (bf16)f.w;
    ((bf16x4*)dst)[i] = v;
  }
}

// ---------------- K5: grouped GEMM layer 1: h = relu(x @ w1e^T + b1e) ----------------
// m97 structure: linear LDS [128][64], global_load_lds width16, XOR-swizzled
// 16B chunks (LDS[row][c8] = global[row][c8 ^ (row&7)]).
__global__ __launch_bounds__(256) void moe_ffn1_kernel(
    const bf16* __restrict__ xb, const bf16* __restrict__ w1b, const float* __restrict__ b1,
    const int* __restrict__ assign_tok, const int* __restrict__ po,
    bf16* __restrict__ h, int chunk_base)
{
  __shared__ bf16 As[BM][BK];
  __shared__ bf16 Bs[BN][BK];
  __shared__ int toks[BM];
  const int po8 = po[NE];
  const int row0 = chunk_base + blockIdx.x * BM;
  if (row0 >= po8) return;
  int e = 0;
  while (row0 >= po[e + 1]) ++e;
  const int bn0 = blockIdx.y * BN;
  const bf16* w1e = w1b + (size_t)e * HH * DD;
  const int tid = threadIdx.x, lane = tid & 63, wave = tid >> 6;
  if (tid < BM) {
    const int s = assign_tok[row0 + tid];
    toks[tid] = s < 0 ? 0 : s;
  }
  __syncthreads();

  // staging source bases: wave handles chunks [wave*4, wave*4+4); chunk c covers
  // rows c*8..c*8+7; lane -> (row = c*8 + lane/8, src col8 = (lane&7) ^ (lane/8))
  const int rin = lane >> 3;
  const int c8s = ((lane & 7) ^ rin) * 8;
  const bf16* asrc[4];
  const bf16* bsrc[4];
  #pragma unroll
  for (int i = 0; i < 4; ++i) {
    const int c = wave * 4 + i;
    const int row = c * 8 + rin;
    asrc[i] = xb + (size_t)toks[row] * DD + c8s;
    bsrc[i] = w1e + (size_t)(bn0 + row) * DD + c8s;
  }

  const int la = lane & 15, hi = lane >> 4;
  const int wm = (wave >> 1) * 64, wn = (wave & 1) * 64;
  f32x4 acc[4][4];
  #pragma unroll
  for (int m = 0; m < 4; ++m)
    #pragma unroll
    for (int n = 0; n < 4; ++n) acc[m][n] = {0.f, 0.f, 0.f, 0.f};

  for (int k0 = 0; k0 < DD; k0 += BK) {
    #pragma unroll
    for (int i = 0; i < 4; ++i) gload16(asrc[i] + k0, &As[(wave * 4 + i) * 8][0]);
    #pragma unroll
    for (int i = 0; i < 4; ++i) gload16(bsrc[i] + k0, &Bs[(wave * 4 + i) * 8][0]);
    __syncthreads();   // compiler drains vmcnt before barrier
    #pragma unroll
    for (int ks = 0; ks < 2; ++ks) {
      bf16x8 af[4], bff[4];
      #pragma unroll
      for (int m = 0; m < 4; ++m) {
        const int row = wm + m * 16 + la;
        const int c8 = (ks * 4 + hi) ^ (row & 7);
        af[m] = *(const bf16x8*)(&As[row][c8 * 8]);
      }
      #pragma unroll
      for (int n = 0; n < 4; ++n) {
        const int row = wn + n * 16 + la;
        const int c8 = (ks * 4 + hi) ^ (row & 7);
        bff[n] = *(const bf16x8*)(&Bs[row][c8 * 8]);
      }
      #pragma unroll
      for (int m = 0; m < 4; ++m)
        #pragma unroll
        for (int n = 0; n < 4; ++n)
          acc[m][n] = __builtin_amdgcn_mfma_f32_16x16x32_bf16(af[m], bff[n], acc[m][n], 0, 0, 0);
    }
    __syncthreads();
  }

  const int hrow0 = row0 - chunk_base;
  #pragma unroll
  for (int n = 0; n < 4; ++n) {
    const int col = bn0 + wn + n * 16 + la;
    const float bb = b1[e * HH + col];
    #pragma unroll
    for (int m = 0; m < 4; ++m) {
      const int rbase = wm + m * 16 + hi * 4;
      #pragma unroll
      for (int r = 0; r < 4; ++r) {
        float v = acc[m][n][r] + bb;
        v = v > 0.f ? v : 0.f;
        h[(size_t)(hrow0 + rbase + r) * HH + col] = (bf16)v;
      }
    }
  }
}

// ---------------- K6: grouped GEMM layer 2 + scaled atomic combine ----------------
__global__ __launch_bounds__(256) void moe_ffn2_kernel(
    const bf16* __restrict__ h, const bf16* __restrict__ w2b, const float* __restrict__ b2,
    const int* __restrict__ assign_tok, const float* __restrict__ slot_coef,
    const int* __restrict__ po, float* __restrict__ out, int chunk_base)
{
  __shared__ bf16 As[BM][BK];
  __shared__ bf16 Bs[BN][BK];
  __shared__ int toks[BM];   // raw (may be -1 for pads)
  const int po8 = po[NE];
  const int row0 = chunk_base + blockIdx.x * BM;
  if (row0 >= po8) return;
  int e = 0;
  while (row0 >= po[e + 1]) ++e;
  const int bn0 = blockIdx.y * BN;
  const bf16* w2e = w2b + (size_t)e * DD * HH;
  const int tid = threadIdx.x, lane = tid & 63, wave = tid >> 6;
  if (tid < BM) toks[tid] = assign_tok[row0 + tid];
  __syncthreads();

  const int rin = lane >> 3;
  const int c8s = ((lane & 7) ^ rin) * 8;
  const bf16* asrc[4];
  const bf16* bsrc[4];
  const int arow0 = row0 - chunk_base;
  #pragma unroll
  for (int i = 0; i < 4; ++i) {
    const int c = wave * 4 + i;
    const int row = c * 8 + rin;
    asrc[i] = h + (size_t)(arow0 + row) * HH + c8s;
    bsrc[i] = w2e + (size_t)(bn0 + row) * HH + c8s;
  }

  const int la = lane & 15, hi = lane >> 4;
  const int wm = (wave >> 1) * 64, wn = (wave & 1) * 64;
  f32x4 acc[4][4];
  #pragma unroll
  for (int m = 0; m < 4; ++m)
    #pragma unroll
    for (int n = 0; n < 4; ++n) acc[m][n] = {0.f, 0.f, 0.f, 0.f};

  for (int k0 = 0; k0 < HH; k0 += BK) {
    #pragma unroll
    for (int i = 0; i < 4; ++i) gload16(asrc[i] + k0, &As[(wave * 4 + i) * 8][0]);
    #pragma unroll
    for (int i = 0; i < 4; ++i) gload16(bsrc[i] + k0, &Bs[(wave * 4 + i) * 8][0]);
    __syncthreads();
    #pragma unroll
    for (int ks = 0; ks < 2; ++ks) {
      bf16x8 af[4], bff[4];
      #pragma unroll
      for (int m = 0; m < 4; ++m) {
        const int row = wm + m * 16 + la;
        const int c8 = (ks * 4 + hi) ^ (row & 7);
        af[m] = *(const bf16x8*)(&As[row][c8 * 8]);
      }
      #pragma unroll
      for (int n = 0; n < 4; ++n) {
        const int row = wn + n * 16 + la;
        const int c8 = (ks * 4 + hi) ^ (row & 7);
        bff[n] = *(const bf16x8*)(&Bs[row][c8 * 8]);
      }
      #pragma unroll
      for (int m = 0; m < 4; ++m)
        #pragma unroll
        for (int n = 0; n < 4; ++n)
          acc[m][n] = __builtin_amdgcn_mfma_f32_16x16x32_bf16(af[m], bff[n], acc[m][n], 0, 0, 0);
    }
    __syncthreads();
  }

  #pragma unroll
  for (int n = 0; n < 4; ++n) {
    const int col = bn0 + wn + n * 16 + la;
    const float bb = b2[e * DD + col];
    #pragma unroll
    for (int m = 0; m < 4; ++m) {
      const int rbase = wm + m * 16 + hi * 4;
      #pragma unroll
      for (int r = 0; r < 4; ++r) {
        const int trow = rbase + r;
        const int tok = toks[trow];
        if (tok >= 0) {
          const float c = slot_coef[row0 + trow];
          atomicAdd(out + (size_t)tok * DD + col, c * (acc[m][n][r] + bb));
        }
      }
    }
  }
}

extern "C" void kernel_launch(void* const* d_in, const int* in_sizes, int n_in,
                              void* d_out, int out_size, void* d_ws, size_t ws_size,
                              hipStream_t stream) {
  const float* x      = (const float*)d_in[0];
  const float* noise  = (const float*)d_in[1];
  const float* gate_w = (const float*)d_in[2];
  const float* gate_b = (const float*)d_in[3];
  const float* var_w  = (const float*)d_in[4];
  const float* var_b  = (const float*)d_in[5];
  const float* w1     = (const float*)d_in[6];
  const float* b1     = (const float*)d_in[7];
  const float* w2     = (const float*)d_in[8];
  const float* b2     = (const float*)d_in[9];
  float* out = (float*)d_out;
  (void)in_sizes; (void)n_in; (void)out_size;

  char* ws = (char*)d_ws;
  size_t off = 0;
  auto alloc = [&](size_t bytes) {
    off = (off + 255) & ~(size_t)255;
    size_t o = off;
    off += bytes;
    return o;
  };
  bf16*  xb         = (bf16*)(ws + alloc((size_t)NTOK * DD * 2));
  float* coef2      = (float*)(ws + alloc((size_t)NTOK * 2 * 4));
  int*   t2e        = (int*)(ws + alloc((size_t)NTOK * 2 * 4));
  int*   counts     = (int*)(ws + alloc(64));   // counts[8] + cnt2[8]
  int*   cnt2       = counts + 8;
  int*   po         = (int*)(ws + alloc(64));
  int*   assign_tok = (int*)(ws + alloc((size_t)SLOT_CAP * 4));
  float* slot_coef  = (float*)(ws + alloc((size_t)SLOT_CAP * 4));
  bf16*  w1b        = (bf16*)(ws + alloc((size_t)NE * HH * DD * 2));  // 64 MB
  bf16*  w2b        = (bf16*)(ws + alloc((size_t)NE * DD * HH * 2));  // 64 MB
  off = (off + 255) & ~(size_t)255;
  const size_t h_avail = ws_size > off ? ws_size - off : 0;
  int chunk_rows = (int)(h_avail / ((size_t)HH * 2));
  chunk_rows = (chunk_rows / BM) * BM;
  if (chunk_rows < BM) chunk_rows = BM;
  if (chunk_rows > SLOT_CAP) chunk_rows = SLOT_CAP;
  bf16* hbuf = (bf16*)(ws + off);

  hipMemsetAsync(counts, 0, 64, stream);
  hipMemsetAsync(assign_tok, 0xFF, (size_t)SLOT_CAP * 4, stream);  // -1
  hipMemsetAsync(out, 0, (size_t)NTOK * DD * 4, stream);

  moe_gate_kernel<<<NTOK, 64, 0, stream>>>(x, noise, gate_w, gate_b, var_w, var_b,
                                           coef2, t2e, counts);
  moe_offsets_kernel<<<1, 64, 0, stream>>>(counts, po);
  moe_scatter_kernel<<<NTOK / 256, 256, 0, stream>>>(t2e, coef2, po, cnt2,
                                                     assign_tok, slot_coef);
  cvt_bf16_kernel<<<2048, 256, 0, stream>>>(x, xb, NTOK * DD / 4);
  cvt_bf16_kernel<<<2048, 256, 0, stream>>>(w1, w1b, NE * HH * DD / 4);
  cvt_bf16_kernel<<<2048, 256, 0, stream>>>(w2, w2b, NE * DD * HH / 4);

  const int rounds = (SLOT_CAP + chunk_rows - 1) / chunk_rows;
  for (int r = 0; r < rounds; ++r) {
    const int cb = r * chunk_rows;
    const int rows_here = (cb + chunk_rows <= SLOT_CAP) ? chunk_rows : (SLOT_CAP - cb);
    dim3 g1(rows_here / BM, HH / BN);
    moe_ffn1_kernel<<<g1, 256, 0, stream>>>(xb, w1b, b1, assign_tok, po, hbuf, cb);
    dim3 g2(rows_here / BM, DD / BN);
    moe_ffn2_kernel<<<g2, 256, 0, stream>>>(hbuf, w2b, b2, assign_tok, slot_coef,
                                            po, out, cb);
  }
}